// Round 13
// baseline (13363.527 us; speedup 1.0000x reference)
//
#include <hip/hip_runtime.h>

constexpr int Bb = 4, Ss = 2048, Hh = 2048;
constexpr int GHh = 1024, G3 = 3072;
constexpr int NTOK = 8192;

// Workspace layout (float offsets)
constexpr size_t WSO_XI = 0;                                  // 8192*3072
constexpr size_t WSO_YS = WSO_XI + (size_t)NTOK * G3;         // 8192*1024 (f32 routing)
constexpr size_t WSO_WINV = WSO_YS + (size_t)NTOK * GHh;      // 1024 inv norms
constexpr size_t WSO_PENTOK = WSO_WINV + 1024;                // 8192
constexpr size_t WSO_PART = WSO_PENTOK + NTOK;                // 256
constexpr size_t WSO_PENS = WSO_PART + 256;                   // 1 (+pad)

// Output layout (float offsets, concatenated reference outputs)
constexpr size_t OUT_MULT = 0;                                // 8192*2
constexpr size_t OUT_SEL = 16384;                             // 8192*2
constexpr size_t OUT_ELOG = 32768;                            // 8192*1024
constexpr size_t OUT_HLAST = OUT_ELOG + (size_t)NTOK * GHh;   // 4096
constexpr size_t OUT_PEN = OUT_HLAST + 4096;                  // 1
constexpr size_t OUT_COS = OUT_PEN + 1;                       // 8192*8
constexpr size_t OUT_ELOSS = OUT_COS + (size_t)NTOK * 8;      // 1

__device__ __forceinline__ float wred(float v) {
#pragma unroll
  for (int o = 32; o > 0; o >>= 1) v += __shfl_xor(v, o, 64);
  return v;
}

// ------- f32 GEMM, double-buffered: C[M][N] = A[M][K] @ W[N][K]^T -------
__global__ __launch_bounds__(256)
void gemm_nt(const float* __restrict__ A, const float* __restrict__ W,
             float* __restrict__ C, int M, int N, int K) {
  __shared__ float As[16][132];
  __shared__ float Ws[16][132];
  const int tid = threadIdx.x;
  const int m0 = blockIdx.x * 128, n0 = blockIdx.y * 128;
  const int tx = tid & 15, ty = tid >> 4;
  const int r0 = tid >> 2, kq0 = tid & 3;              // loader slot u=0
  const int r1 = (tid + 256) >> 2, kq1 = tid & 3;      // loader slot u=1
  float acc[8][8];
#pragma unroll
  for (int i = 0; i < 8; ++i)
#pragma unroll
    for (int j = 0; j < 8; ++j) acc[i][j] = 0.f;

  float4 pa0, pa1, pw0, pw1;
  // prefetch tile kt=0 into registers
  pa0 = *reinterpret_cast<const float4*>(&A[(size_t)(m0 + r0) * K + kq0 * 4]);
  pw0 = *reinterpret_cast<const float4*>(&W[(size_t)(n0 + r0) * K + kq0 * 4]);
  pa1 = *reinterpret_cast<const float4*>(&A[(size_t)(m0 + r1) * K + kq1 * 4]);
  pw1 = *reinterpret_cast<const float4*>(&W[(size_t)(n0 + r1) * K + kq1 * 4]);

  for (int kt = 0; kt < K; kt += 16) {
    __syncthreads();                        // previous compute done reading LDS
    As[kq0 * 4 + 0][r0] = pa0.x; As[kq0 * 4 + 1][r0] = pa0.y;
    As[kq0 * 4 + 2][r0] = pa0.z; As[kq0 * 4 + 3][r0] = pa0.w;
    Ws[kq0 * 4 + 0][r0] = pw0.x; Ws[kq0 * 4 + 1][r0] = pw0.y;
    Ws[kq0 * 4 + 2][r0] = pw0.z; Ws[kq0 * 4 + 3][r0] = pw0.w;
    As[kq1 * 4 + 0][r1] = pa1.x; As[kq1 * 4 + 1][r1] = pa1.y;
    As[kq1 * 4 + 2][r1] = pa1.z; As[kq1 * 4 + 3][r1] = pa1.w;
    Ws[kq1 * 4 + 0][r1] = pw1.x; Ws[kq1 * 4 + 1][r1] = pw1.y;
    Ws[kq1 * 4 + 2][r1] = pw1.z; Ws[kq1 * 4 + 3][r1] = pw1.w;
    __syncthreads();                        // LDS tile ready
    if (kt + 16 < K) {                      // prefetch next tile (overlaps compute)
      const int kn = kt + 16;
      pa0 = *reinterpret_cast<const float4*>(&A[(size_t)(m0 + r0) * K + kn + kq0 * 4]);
      pw0 = *reinterpret_cast<const float4*>(&W[(size_t)(n0 + r0) * K + kn + kq0 * 4]);
      pa1 = *reinterpret_cast<const float4*>(&A[(size_t)(m0 + r1) * K + kn + kq1 * 4]);
      pw1 = *reinterpret_cast<const float4*>(&W[(size_t)(n0 + r1) * K + kn + kq1 * 4]);
    }
#pragma unroll
    for (int k = 0; k < 16; ++k) {
      const float4 a0 = *reinterpret_cast<const float4*>(&As[k][ty * 8]);
      const float4 a1 = *reinterpret_cast<const float4*>(&As[k][ty * 8 + 4]);
      const float4 w0 = *reinterpret_cast<const float4*>(&Ws[k][tx * 8]);
      const float4 w1 = *reinterpret_cast<const float4*>(&Ws[k][tx * 8 + 4]);
      const float a[8] = {a0.x, a0.y, a0.z, a0.w, a1.x, a1.y, a1.z, a1.w};
      const float w[8] = {w0.x, w0.y, w0.z, w0.w, w1.x, w1.y, w1.z, w1.w};
#pragma unroll
      for (int i = 0; i < 8; ++i)
#pragma unroll
        for (int j = 0; j < 8; ++j) acc[i][j] += a[i] * w[j];
    }
  }
#pragma unroll
  for (int i = 0; i < 8; ++i) {
    const size_t row = (size_t)(m0 + ty * 8 + i);
    float4 v0 = {acc[i][0], acc[i][1], acc[i][2], acc[i][3]};
    float4 v1 = {acc[i][4], acc[i][5], acc[i][6], acc[i][7]};
    *reinterpret_cast<float4*>(&C[row * N + n0 + tx * 8]) = v0;
    *reinterpret_cast<float4*>(&C[row * N + n0 + tx * 8 + 4]) = v1;
  }
}

// ---- GRU single step (graph node per t). Weight regs prefetched pre-barrier. ----
__global__ __launch_bounds__(256)
void gru_step(const float* __restrict__ xi, const float* __restrict__ whh,
              const float* __restrict__ hprev, size_t hstride,
              float* __restrict__ ys, float* __restrict__ hlast, int t) {
  __shared__ float hs[Bb * GHh];               // 16 KB
  const int tid = threadIdx.x, wg = blockIdx.x;
  const int gl = tid >> 6, lane = tid & 63;
  const int g = wg * 4 + gl;

  // weight prefetch (independent of h): overlaps staging + barrier latency
  float4 w0[4], w1[4], w2[4];
#pragma unroll
  for (int i = 0; i < 4; ++i) {
    const int k = lane * 4 + i * 256;
    w0[i] = *reinterpret_cast<const float4*>(&whh[(size_t)g * GHh + k]);
    w1[i] = *reinterpret_cast<const float4*>(&whh[(size_t)(GHh + g) * GHh + k]);
    w2[i] = *reinterpret_cast<const float4*>(&whh[(size_t)(2 * GHh + g) * GHh + k]);
  }
  // xi prefetch for finalize lanes (lane<4 -> b=lane)
  float xr_ = 0.f, xz_ = 0.f, xn_ = 0.f;
  if (lane < 4) {
    const size_t base = (size_t)(lane * Ss + t) * G3 + g;
    xr_ = xi[base]; xz_ = xi[base + GHh]; xn_ = xi[base + 2 * GHh];
  }
  // stage h_{t-1}
#pragma unroll
  for (int b = 0; b < 4; ++b) {
    *reinterpret_cast<float4*>(&hs[b * GHh + tid * 4]) =
        *reinterpret_cast<const float4*>(&hprev[(size_t)b * hstride + tid * 4]);
  }
  __syncthreads();

  float acc[3][4];
#pragma unroll
  for (int gate = 0; gate < 3; ++gate)
#pragma unroll
    for (int b = 0; b < 4; ++b) acc[gate][b] = 0.f;
#pragma unroll
  for (int i = 0; i < 4; ++i) {
    const int k = lane * 4 + i * 256;
#pragma unroll
    for (int b = 0; b < 4; ++b) {
      const float4 hv = *reinterpret_cast<const float4*>(&hs[b * GHh + k]);
      acc[0][b] += w0[i].x * hv.x + w0[i].y * hv.y + w0[i].z * hv.z + w0[i].w * hv.w;
      acc[1][b] += w1[i].x * hv.x + w1[i].y * hv.y + w1[i].z * hv.z + w1[i].w * hv.w;
      acc[2][b] += w2[i].x * hv.x + w2[i].y * hv.y + w2[i].z * hv.z + w2[i].w * hv.w;
    }
  }
  // full 64-lane butterfly reduction
#pragma unroll
  for (int o = 1; o < 64; o <<= 1) {
#pragma unroll
    for (int gate = 0; gate < 3; ++gate)
#pragma unroll
      for (int b = 0; b < 4; ++b)
        acc[gate][b] += __shfl_xor(acc[gate][b], o, 64);
  }
  if (lane < 4) {
    const int b = lane;
    const float rg = 1.f / (1.f + __expf(-(xr_ + acc[0][b])));
    const float zg = 1.f / (1.f + __expf(-(xz_ + acc[1][b])));
    const float ng = tanhf(xn_ + rg * acc[2][b]);
    const float hnew = (1.f - zg) * ng + zg * hs[b * GHh + g];
    // sc1 store: bypass dirty-L2 so end-of-kernel drain is short
    __hip_atomic_store(&ys[((size_t)(b * Ss + t) << 10) + g], hnew,
                       __ATOMIC_RELAXED, __HIP_MEMORY_SCOPE_AGENT);
    if (t == Ss - 1) hlast[b * GHh + g] = hnew;
  }
}

// ---------------- per-token: l2norm, gram penalty, cosine ----------------
__global__ __launch_bounds__(256)
void token_kernel(const float* __restrict__ ys, const float* __restrict__ elog,
                  float* __restrict__ cosout, float* __restrict__ pen_tok) {
  const int lane = threadIdx.x & 63;
  const int tok = blockIdx.x * 4 + (threadIdx.x >> 6);
  const float* rp = ys + (size_t)tok * GHh;
  const float* ep = elog + (size_t)tok * GHh;
  float rr[8][2], el[8][2];
#pragma unroll
  for (int e = 0; e < 8; ++e) {
    rr[e][0] = rp[e * 128 + lane]; rr[e][1] = rp[e * 128 + 64 + lane];
    el[e][0] = ep[e * 128 + lane]; el[e][1] = ep[e * 128 + 64 + lane];
  }
#pragma unroll
  for (int e = 0; e < 8; ++e) {
    const float s = wred(rr[e][0] * rr[e][0] + rr[e][1] * rr[e][1]);
    const float inv = 1.f / fmaxf(sqrtf(s), 1e-12f);
    rr[e][0] *= inv; rr[e][1] *= inv;
  }
  float pen = 0.f;
  for (int e = 0; e < 8; ++e) {
    float srow = 0.f;
    for (int f = 0; f < 8; ++f) {
      const float gv = wred(rr[e][0] * rr[f][0] + rr[e][1] * rr[f][1]);
      const float dv = gv - (e == f ? 1.f : 0.f);
      srow += dv * dv;
    }
    pen += srow / fmaxf(srow, 1e-24f);
  }
#pragma unroll
  for (int e = 0; e < 8; ++e) {
    const float dot = wred(el[e][0] * rr[e][0] + el[e][1] * rr[e][1]);
    const float na2 = wred(el[e][0] * el[e][0] + el[e][1] * el[e][1]);
    const float nb2 = wred(rr[e][0] * rr[e][0] + rr[e][1] * rr[e][1]);
    const float cs = dot / (fmaxf(sqrtf(na2), 1e-8f) * fmaxf(sqrtf(nb2), 1e-8f));
    if (lane == e) cosout[(size_t)tok * 8 + e] = 1.f - cs;
  }
  if (lane == 0) pen_tok[tok] = pen;
}

// ---------------- expr_w row inverse norms only ----------------
__global__ __launch_bounds__(256)
void wn_norms(const float* __restrict__ w, float* __restrict__ winv) {
  const int lane = threadIdx.x & 63;
  const int row = blockIdx.x * 4 + (threadIdx.x >> 6);
  const float* src = w + (size_t)row * Hh;
  float s = 0.f;
  for (int c = lane; c < Hh; c += 64) { const float v = src[c]; s += v * v; }
  s = wred(s);
  if (lane == 0) winv[row] = 1.f / fmaxf(sqrtf(s), 1e-12f);
}

// ------- gram(w) orthogonality loss partials, scaled by inv norms at the end -------
__global__ __launch_bounds__(256)
void gw_loss(const float* __restrict__ w, const float* __restrict__ winv,
             float* __restrict__ partial) {
  __shared__ float As[32][68];
  __shared__ float Bs[32][68];
  __shared__ float rbuf[256];
  const int tid = threadIdx.x;
  const int m0 = blockIdx.x * 64, n0 = blockIdx.y * 64;
  const int tx = tid & 15, ty = tid >> 4;
  float acc[4][4];
#pragma unroll
  for (int i = 0; i < 4; ++i)
#pragma unroll
    for (int j = 0; j < 4; ++j) acc[i][j] = 0.f;

  for (int kt = 0; kt < Hh; kt += 32) {
#pragma unroll
    for (int li = tid; li < 512; li += 256) {
      const int r = li >> 3, kq = li & 7;
      const float4 av = *reinterpret_cast<const float4*>(&w[(size_t)(m0 + r) * Hh + kt + kq * 4]);
      As[kq * 4 + 0][r] = av.x; As[kq * 4 + 1][r] = av.y;
      As[kq * 4 + 2][r] = av.z; As[kq * 4 + 3][r] = av.w;
      const float4 bv = *reinterpret_cast<const float4*>(&w[(size_t)(n0 + r) * Hh + kt + kq * 4]);
      Bs[kq * 4 + 0][r] = bv.x; Bs[kq * 4 + 1][r] = bv.y;
      Bs[kq * 4 + 2][r] = bv.z; Bs[kq * 4 + 3][r] = bv.w;
    }
    __syncthreads();
#pragma unroll
    for (int k = 0; k < 32; ++k) {
      const float4 a4 = *reinterpret_cast<const float4*>(&As[k][ty * 4]);
      const float4 b4 = *reinterpret_cast<const float4*>(&Bs[k][tx * 4]);
      const float a[4] = {a4.x, a4.y, a4.z, a4.w};
      const float b[4] = {b4.x, b4.y, b4.z, b4.w};
#pragma unroll
      for (int i = 0; i < 4; ++i)
#pragma unroll
        for (int j = 0; j < 4; ++j) acc[i][j] += a[i] * b[j];
    }
    __syncthreads();
  }
  float invm[4], invn[4];
#pragma unroll
  for (int i = 0; i < 4; ++i) { invm[i] = winv[m0 + ty * 4 + i]; invn[i] = winv[n0 + tx * 4 + i]; }
  float local = 0.f;
#pragma unroll
  for (int i = 0; i < 4; ++i)
#pragma unroll
    for (int j = 0; j < 4; ++j) {
      const float d = acc[i][j] * invm[i] * invn[j] -
                      ((m0 + ty * 4 + i) == (n0 + tx * 4 + j) ? 1.f : 0.f);
      local += d * d;
    }
  rbuf[tid] = local;
  __syncthreads();
  for (int o = 128; o > 0; o >>= 1) {
    if (tid < o) rbuf[tid] += rbuf[tid + o];
    __syncthreads();
  }
  if (tid == 0) partial[blockIdx.y * 16 + blockIdx.x] = rbuf[0];
}

// ---------------- scalar reductions (deterministic, fixed order) ----------------
__global__ __launch_bounds__(256)
void scalars_kernel(const float* __restrict__ pen_tok, const float* __restrict__ partial,
                    float* __restrict__ out_pen, float* __restrict__ ws_pen,
                    float* __restrict__ out_eloss) {
  __shared__ float sm[256];
  const int tid = threadIdx.x;
  float s = 0.f;
  for (int i = tid; i < NTOK; i += 256) s += pen_tok[i];
  sm[tid] = s;
  __syncthreads();
  for (int o = 128; o > 0; o >>= 1) {
    if (tid < o) sm[tid] += sm[tid + o];
    __syncthreads();
  }
  if (tid == 0) { const float p = sm[0] / (float)NTOK; out_pen[0] = p; ws_pen[0] = p; }
  __syncthreads();
  sm[tid] = partial[tid];
  __syncthreads();
  for (int o = 128; o > 0; o >>= 1) {
    if (tid < o) sm[tid] += sm[tid + o];
    __syncthreads();
  }
  if (tid == 0) out_eloss[0] = sm[0] / (1024.f * 1024.f);
}

// ---------------- top-k(2) + softmax ----------------
__global__ __launch_bounds__(256)
void topk_kernel(const float* __restrict__ cosf, const float* __restrict__ pens,
                 float* __restrict__ mult, float* __restrict__ sel) {
  const int tok = blockIdx.x * 256 + threadIdx.x;
  const float p = 1.f + pens[0];
  float sc[8];
#pragma unroll
  for (int e = 0; e < 8; ++e) sc[e] = cosf[(size_t)tok * 8 + e] * p;
  int i0 = 0; float v0 = sc[0];
#pragma unroll
  for (int e = 1; e < 8; ++e) if (sc[e] > v0) { v0 = sc[e]; i0 = e; }
  int i1 = -1; float v1 = -3.4e38f;
#pragma unroll
  for (int e = 0; e < 8; ++e) if (e != i0 && sc[e] > v1) { v1 = sc[e]; i1 = e; }
  const float ex = __expf(v1 - v0);
  const float den = 1.f + ex;
  mult[(size_t)tok * 2] = 1.f / den;
  mult[(size_t)tok * 2 + 1] = ex / den;
  sel[(size_t)tok * 2] = (float)i0;
  sel[(size_t)tok * 2 + 1] = (float)i1;
}

extern "C" void kernel_launch(void* const* d_in, const int* in_sizes, int n_in,
                              void* d_out, int out_size, void* d_ws, size_t ws_size,
                              hipStream_t stream) {
  (void)in_sizes; (void)n_in; (void)out_size; (void)ws_size;
  const float* x = (const float*)d_in[0];
  const float* hn = (const float*)d_in[1];
  const float* w_ih = (const float*)d_in[2];
  const float* w_hh = (const float*)d_in[3];
  const float* expr_w = (const float*)d_in[4];
  float* out = (float*)d_out;
  float* ws = (float*)d_ws;

  float* xi = ws + WSO_XI;
  float* ysb = ws + WSO_YS;
  float* winv = ws + WSO_WINV;
  float* pen_tok = ws + WSO_PENTOK;
  float* partial = ws + WSO_PART;
  float* pens = ws + WSO_PENS;

  gemm_nt<<<dim3(64, 24), 256, 0, stream>>>(x, w_ih, xi, NTOK, G3, Hh);
  const float* hp = hn;
  size_t hstr = GHh;
  for (int t = 0; t < Ss; ++t) {
    gru_step<<<dim3(256), 256, 0, stream>>>(xi, w_hh, hp, hstr, ysb, out + OUT_HLAST, t);
    hp = ysb + (size_t)t * GHh;
    hstr = (size_t)Ss * GHh;
  }
  gemm_nt<<<dim3(64, 8), 256, 0, stream>>>(x, expr_w, out + OUT_ELOG, NTOK, GHh, Hh);
  wn_norms<<<dim3(256), 256, 0, stream>>>(expr_w, winv);
  gw_loss<<<dim3(16, 16), 256, 0, stream>>>(expr_w, winv, partial);
  token_kernel<<<dim3(2048), 256, 0, stream>>>(ysb, out + OUT_ELOG, out + OUT_COS, pen_tok);
  scalars_kernel<<<dim3(1), 256, 0, stream>>>(pen_tok, partial, out + OUT_PEN, pens,
                                              out + OUT_ELOSS);
  topk_kernel<<<dim3(32), 256, 0, stream>>>(out + OUT_COS, pens, out + OUT_MULT, out + OUT_SEL);
}

// Round 14
// 12426.133 us; speedup vs baseline: 1.0754x; 1.0754x over previous
//
#include <hip/hip_runtime.h>

constexpr int Bb = 4, Ss = 2048, Hh = 2048;
constexpr int GHh = 1024, G3 = 3072;
constexpr int NTOK = 8192;

// Workspace layout (float offsets)
constexpr size_t WSO_XI = 0;                                  // 8192*3072
constexpr size_t WSO_YS = WSO_XI + (size_t)NTOK * G3;         // 8192*1024 (f32 routing)
constexpr size_t WSO_WINV = WSO_YS + (size_t)NTOK * GHh;      // 1024 inv norms
constexpr size_t WSO_PENTOK = WSO_WINV + 1024;                // 8192
constexpr size_t WSO_PART = WSO_PENTOK + NTOK;                // 256
constexpr size_t WSO_PENS = WSO_PART + 256;                   // 1 (+pad)

// Output layout (float offsets, concatenated reference outputs)
constexpr size_t OUT_MULT = 0;                                // 8192*2
constexpr size_t OUT_SEL = 16384;                             // 8192*2
constexpr size_t OUT_ELOG = 32768;                            // 8192*1024
constexpr size_t OUT_HLAST = OUT_ELOG + (size_t)NTOK * GHh;   // 4096
constexpr size_t OUT_PEN = OUT_HLAST + 4096;                  // 1
constexpr size_t OUT_COS = OUT_PEN + 1;                       // 8192*8
constexpr size_t OUT_ELOSS = OUT_COS + (size_t)NTOK * 8;      // 1

__device__ __forceinline__ float wred(float v) {
#pragma unroll
  for (int o = 32; o > 0; o >>= 1) v += __shfl_xor(v, o, 64);
  return v;
}

// ---------------- f32 GEMM (r12-proven): C[M][N] = A[M][K] @ W[N][K]^T ----------------
__global__ __launch_bounds__(256)
void gemm_nt(const float* __restrict__ A, const float* __restrict__ W,
             float* __restrict__ C, int M, int N, int K) {
  __shared__ float As[16][132];
  __shared__ float Ws[16][132];
  const int tid = threadIdx.x;
  const int m0 = blockIdx.x * 128, n0 = blockIdx.y * 128;
  const int tx = tid & 15, ty = tid >> 4;
  float acc[8][8];
#pragma unroll
  for (int i = 0; i < 8; ++i)
#pragma unroll
    for (int j = 0; j < 8; ++j) acc[i][j] = 0.f;

  for (int kt = 0; kt < K; kt += 16) {
#pragma unroll
    for (int li = tid; li < 512; li += 256) {
      const int r = li >> 2, kq = li & 3;
      const float4 av = *reinterpret_cast<const float4*>(&A[(size_t)(m0 + r) * K + kt + kq * 4]);
      As[kq * 4 + 0][r] = av.x; As[kq * 4 + 1][r] = av.y;
      As[kq * 4 + 2][r] = av.z; As[kq * 4 + 3][r] = av.w;
      const float4 wv = *reinterpret_cast<const float4*>(&W[(size_t)(n0 + r) * K + kt + kq * 4]);
      Ws[kq * 4 + 0][r] = wv.x; Ws[kq * 4 + 1][r] = wv.y;
      Ws[kq * 4 + 2][r] = wv.z; Ws[kq * 4 + 3][r] = wv.w;
    }
    __syncthreads();
#pragma unroll
    for (int k = 0; k < 16; ++k) {
      const float4 a0 = *reinterpret_cast<const float4*>(&As[k][ty * 8]);
      const float4 a1 = *reinterpret_cast<const float4*>(&As[k][ty * 8 + 4]);
      const float4 w0 = *reinterpret_cast<const float4*>(&Ws[k][tx * 8]);
      const float4 w1 = *reinterpret_cast<const float4*>(&Ws[k][tx * 8 + 4]);
      const float a[8] = {a0.x, a0.y, a0.z, a0.w, a1.x, a1.y, a1.z, a1.w};
      const float w[8] = {w0.x, w0.y, w0.z, w0.w, w1.x, w1.y, w1.z, w1.w};
#pragma unroll
      for (int i = 0; i < 8; ++i)
#pragma unroll
        for (int j = 0; j < 8; ++j) acc[i][j] += a[i] * w[j];
    }
    __syncthreads();
  }
#pragma unroll
  for (int i = 0; i < 8; ++i) {
    const size_t row = (size_t)(m0 + ty * 8 + i);
    float4 v0 = {acc[i][0], acc[i][1], acc[i][2], acc[i][3]};
    float4 v1 = {acc[i][4], acc[i][5], acc[i][6], acc[i][7]};
    *reinterpret_cast<float4*>(&C[row * N + n0 + tx * 8]) = v0;
    *reinterpret_cast<float4*>(&C[row * N + n0 + tx * 8 + 4]) = v1;
  }
}

// ---- GRU single step (r12-proven ordering; branchless hprev) ----
// grid 256 WGs x 256 thr. WG wg owns outputs g in [wg*4, wg*4+4), all 4 batches.
__global__ __launch_bounds__(256)
void gru_step(const float* __restrict__ xi, const float* __restrict__ whh,
              const float* __restrict__ hprev, size_t hstride,
              float* __restrict__ ys, float* __restrict__ hlast, int t) {
  __shared__ float hs[Bb * GHh];               // 16 KB
  const int tid = threadIdx.x, wg = blockIdx.x;
  const int gl = tid >> 6, lane = tid & 63;
  const int g = wg * 4 + gl;

  // xi prefetch for finalize lanes (lane<4 -> b=lane)
  float xr_ = 0.f, xz_ = 0.f, xn_ = 0.f;
  if (lane < 4) {
    const size_t base = (size_t)(lane * Ss + t) * G3 + g;
    xr_ = xi[base]; xz_ = xi[base + GHh]; xn_ = xi[base + 2 * GHh];
  }
  // stage h_{t-1} FIRST (critical path), then barrier
#pragma unroll
  for (int b = 0; b < 4; ++b) {
    *reinterpret_cast<float4*>(&hs[b * GHh + tid * 4]) =
        *reinterpret_cast<const float4*>(&hprev[(size_t)b * hstride + tid * 4]);
  }
  __syncthreads();

  // weights loaded inside the compute loop (overlap naturally with FMA issue)
  float acc[3][4];
#pragma unroll
  for (int gate = 0; gate < 3; ++gate)
#pragma unroll
    for (int b = 0; b < 4; ++b) acc[gate][b] = 0.f;
#pragma unroll
  for (int i = 0; i < 4; ++i) {
    const int k = lane * 4 + i * 256;
    const float4 w0 = *reinterpret_cast<const float4*>(&whh[(size_t)g * GHh + k]);
    const float4 w1 = *reinterpret_cast<const float4*>(&whh[(size_t)(GHh + g) * GHh + k]);
    const float4 w2 = *reinterpret_cast<const float4*>(&whh[(size_t)(2 * GHh + g) * GHh + k]);
#pragma unroll
    for (int b = 0; b < 4; ++b) {
      const float4 hv = *reinterpret_cast<const float4*>(&hs[b * GHh + k]);
      acc[0][b] += w0.x * hv.x + w0.y * hv.y + w0.z * hv.z + w0.w * hv.w;
      acc[1][b] += w1.x * hv.x + w1.y * hv.y + w1.z * hv.z + w1.w * hv.w;
      acc[2][b] += w2.x * hv.x + w2.y * hv.y + w2.z * hv.z + w2.w * hv.w;
    }
  }
  // full 64-lane butterfly reduction
#pragma unroll
  for (int o = 1; o < 64; o <<= 1) {
#pragma unroll
    for (int gate = 0; gate < 3; ++gate)
#pragma unroll
      for (int b = 0; b < 4; ++b)
        acc[gate][b] += __shfl_xor(acc[gate][b], o, 64);
  }
  if (lane < 4) {
    const int b = lane;
    const float rg = 1.f / (1.f + __expf(-(xr_ + acc[0][b])));
    const float zg = 1.f / (1.f + __expf(-(xz_ + acc[1][b])));
    const float ng = tanhf(xn_ + rg * acc[2][b]);
    const float hnew = (1.f - zg) * ng + zg * hs[b * GHh + g];
    ys[((size_t)(b * Ss + t) << 10) + g] = hnew;   // plain store (r12-proven)
    if (t == Ss - 1) hlast[b * GHh + g] = hnew;
  }
}

// ---------------- per-token: l2norm, gram penalty, cosine ----------------
__global__ __launch_bounds__(256)
void token_kernel(const float* __restrict__ ys, const float* __restrict__ elog,
                  float* __restrict__ cosout, float* __restrict__ pen_tok) {
  const int lane = threadIdx.x & 63;
  const int tok = blockIdx.x * 4 + (threadIdx.x >> 6);
  const float* rp = ys + (size_t)tok * GHh;
  const float* ep = elog + (size_t)tok * GHh;
  float rr[8][2], el[8][2];
#pragma unroll
  for (int e = 0; e < 8; ++e) {
    rr[e][0] = rp[e * 128 + lane]; rr[e][1] = rp[e * 128 + 64 + lane];
    el[e][0] = ep[e * 128 + lane]; el[e][1] = ep[e * 128 + 64 + lane];
  }
#pragma unroll
  for (int e = 0; e < 8; ++e) {
    const float s = wred(rr[e][0] * rr[e][0] + rr[e][1] * rr[e][1]);
    const float inv = 1.f / fmaxf(sqrtf(s), 1e-12f);
    rr[e][0] *= inv; rr[e][1] *= inv;
  }
  float pen = 0.f;
  for (int e = 0; e < 8; ++e) {
    float srow = 0.f;
    for (int f = 0; f < 8; ++f) {
      const float gv = wred(rr[e][0] * rr[f][0] + rr[e][1] * rr[f][1]);
      const float dv = gv - (e == f ? 1.f : 0.f);
      srow += dv * dv;
    }
    pen += srow / fmaxf(srow, 1e-24f);
  }
#pragma unroll
  for (int e = 0; e < 8; ++e) {
    const float dot = wred(el[e][0] * rr[e][0] + el[e][1] * rr[e][1]);
    const float na2 = wred(el[e][0] * el[e][0] + el[e][1] * el[e][1]);
    const float nb2 = wred(rr[e][0] * rr[e][0] + rr[e][1] * rr[e][1]);
    const float cs = dot / (fmaxf(sqrtf(na2), 1e-8f) * fmaxf(sqrtf(nb2), 1e-8f));
    if (lane == e) cosout[(size_t)tok * 8 + e] = 1.f - cs;
  }
  if (lane == 0) pen_tok[tok] = pen;
}

// ---------------- expr_w row inverse norms only ----------------
__global__ __launch_bounds__(256)
void wn_norms(const float* __restrict__ w, float* __restrict__ winv) {
  const int lane = threadIdx.x & 63;
  const int row = blockIdx.x * 4 + (threadIdx.x >> 6);
  const float* src = w + (size_t)row * Hh;
  float s = 0.f;
  for (int c = lane; c < Hh; c += 64) { const float v = src[c]; s += v * v; }
  s = wred(s);
  if (lane == 0) winv[row] = 1.f / fmaxf(sqrtf(s), 1e-12f);
}

// ------- gram(w) orthogonality loss partials, scaled by inv norms at the end -------
__global__ __launch_bounds__(256)
void gw_loss(const float* __restrict__ w, const float* __restrict__ winv,
             float* __restrict__ partial) {
  __shared__ float As[32][68];
  __shared__ float Bs[32][68];
  __shared__ float rbuf[256];
  const int tid = threadIdx.x;
  const int m0 = blockIdx.x * 64, n0 = blockIdx.y * 64;
  const int tx = tid & 15, ty = tid >> 4;
  float acc[4][4];
#pragma unroll
  for (int i = 0; i < 4; ++i)
#pragma unroll
    for (int j = 0; j < 4; ++j) acc[i][j] = 0.f;

  for (int kt = 0; kt < Hh; kt += 32) {
#pragma unroll
    for (int li = tid; li < 512; li += 256) {
      const int r = li >> 3, kq = li & 7;
      const float4 av = *reinterpret_cast<const float4*>(&w[(size_t)(m0 + r) * Hh + kt + kq * 4]);
      As[kq * 4 + 0][r] = av.x; As[kq * 4 + 1][r] = av.y;
      As[kq * 4 + 2][r] = av.z; As[kq * 4 + 3][r] = av.w;
      const float4 bv = *reinterpret_cast<const float4*>(&w[(size_t)(n0 + r) * Hh + kt + kq * 4]);
      Bs[kq * 4 + 0][r] = bv.x; Bs[kq * 4 + 1][r] = bv.y;
      Bs[kq * 4 + 2][r] = bv.z; Bs[kq * 4 + 3][r] = bv.w;
    }
    __syncthreads();
#pragma unroll
    for (int k = 0; k < 32; ++k) {
      const float4 a4 = *reinterpret_cast<const float4*>(&As[k][ty * 4]);
      const float4 b4 = *reinterpret_cast<const float4*>(&Bs[k][tx * 4]);
      const float a[4] = {a4.x, a4.y, a4.z, a4.w};
      const float b[4] = {b4.x, b4.y, b4.z, b4.w};
#pragma unroll
      for (int i = 0; i < 4; ++i)
#pragma unroll
        for (int j = 0; j < 4; ++j) acc[i][j] += a[i] * b[j];
    }
    __syncthreads();
  }
  float invm[4], invn[4];
#pragma unroll
  for (int i = 0; i < 4; ++i) { invm[i] = winv[m0 + ty * 4 + i]; invn[i] = winv[n0 + tx * 4 + i]; }
  float local = 0.f;
#pragma unroll
  for (int i = 0; i < 4; ++i)
#pragma unroll
    for (int j = 0; j < 4; ++j) {
      const float d = acc[i][j] * invm[i] * invn[j] -
                      ((m0 + ty * 4 + i) == (n0 + tx * 4 + j) ? 1.f : 0.f);
      local += d * d;
    }
  rbuf[tid] = local;
  __syncthreads();
  for (int o = 128; o > 0; o >>= 1) {
    if (tid < o) rbuf[tid] += rbuf[tid + o];
    __syncthreads();
  }
  if (tid == 0) partial[blockIdx.y * 16 + blockIdx.x] = rbuf[0];
}

// ---------------- scalar reductions (deterministic, fixed order) ----------------
__global__ __launch_bounds__(256)
void scalars_kernel(const float* __restrict__ pen_tok, const float* __restrict__ partial,
                    float* __restrict__ out_pen, float* __restrict__ ws_pen,
                    float* __restrict__ out_eloss) {
  __shared__ float sm[256];
  const int tid = threadIdx.x;
  float s = 0.f;
  for (int i = tid; i < NTOK; i += 256) s += pen_tok[i];
  sm[tid] = s;
  __syncthreads();
  for (int o = 128; o > 0; o >>= 1) {
    if (tid < o) sm[tid] += sm[tid + o];
    __syncthreads();
  }
  if (tid == 0) { const float p = sm[0] / (float)NTOK; out_pen[0] = p; ws_pen[0] = p; }
  __syncthreads();
  sm[tid] = partial[tid];
  __syncthreads();
  for (int o = 128; o > 0; o >>= 1) {
    if (tid < o) sm[tid] += sm[tid + o];
    __syncthreads();
  }
  if (tid == 0) out_eloss[0] = sm[0] / (1024.f * 1024.f);
}

// ---------------- top-k(2) + softmax ----------------
__global__ __launch_bounds__(256)
void topk_kernel(const float* __restrict__ cosf, const float* __restrict__ pens,
                 float* __restrict__ mult, float* __restrict__ sel) {
  const int tok = blockIdx.x * 256 + threadIdx.x;
  const float p = 1.f + pens[0];
  float sc[8];
#pragma unroll
  for (int e = 0; e < 8; ++e) sc[e] = cosf[(size_t)tok * 8 + e] * p;
  int i0 = 0; float v0 = sc[0];
#pragma unroll
  for (int e = 1; e < 8; ++e) if (sc[e] > v0) { v0 = sc[e]; i0 = e; }
  int i1 = -1; float v1 = -3.4e38f;
#pragma unroll
  for (int e = 0; e < 8; ++e) if (e != i0 && sc[e] > v1) { v1 = sc[e]; i1 = e; }
  const float ex = __expf(v1 - v0);
  const float den = 1.f + ex;
  mult[(size_t)tok * 2] = 1.f / den;
  mult[(size_t)tok * 2 + 1] = ex / den;
  sel[(size_t)tok * 2] = (float)i0;
  sel[(size_t)tok * 2 + 1] = (float)i1;
}

extern "C" void kernel_launch(void* const* d_in, const int* in_sizes, int n_in,
                              void* d_out, int out_size, void* d_ws, size_t ws_size,
                              hipStream_t stream) {
  (void)in_sizes; (void)n_in; (void)out_size; (void)ws_size;
  const float* x = (const float*)d_in[0];
  const float* hn = (const float*)d_in[1];
  const float* w_ih = (const float*)d_in[2];
  const float* w_hh = (const float*)d_in[3];
  const float* expr_w = (const float*)d_in[4];
  float* out = (float*)d_out;
  float* ws = (float*)d_ws;

  float* xi = ws + WSO_XI;
  float* ysb = ws + WSO_YS;
  float* winv = ws + WSO_WINV;
  float* pen_tok = ws + WSO_PENTOK;
  float* partial = ws + WSO_PART;
  float* pens = ws + WSO_PENS;

  gemm_nt<<<dim3(64, 24), 256, 0, stream>>>(x, w_ih, xi, NTOK, G3, Hh);
  const float* hp = hn;
  size_t hstr = GHh;
  for (int t = 0; t < Ss; ++t) {
    gru_step<<<dim3(256), 256, 0, stream>>>(xi, w_hh, hp, hstr, ysb, out + OUT_HLAST, t);
    hp = ysb + (size_t)t * GHh;
    hstr = (size_t)Ss * GHh;
  }
  gemm_nt<<<dim3(64, 8), 256, 0, stream>>>(x, expr_w, out + OUT_ELOG, NTOK, GHh, Hh);
  wn_norms<<<dim3(256), 256, 0, stream>>>(expr_w, winv);
  gw_loss<<<dim3(16, 16), 256, 0, stream>>>(expr_w, winv, partial);
  token_kernel<<<dim3(2048), 256, 0, stream>>>(ysb, out + OUT_ELOG, out + OUT_COS, pen_tok);
  scalars_kernel<<<dim3(1), 256, 0, stream>>>(pen_tok, partial, out + OUT_PEN, pens,
                                              out + OUT_ELOSS);
  topk_kernel<<<dim3(32), 256, 0, stream>>>(out + OUT_COS, pens, out + OUT_MULT, out + OUT_SEL);
}